// Round 1
// baseline (1453.657 us; speedup 1.0000x reference)
//
#include <hip/hip_runtime.h>

#define NEGV (-1.0e9f)

// ---------------------------------------------------------------------------
// Tiled fp32 GEMM: C[M,N] = A[M,Kd] @ B[Kd,N] (+ bias), row-major, batched via
// blockIdx.z with element strides. If kLimitCausal != 0, the k-loop is limited
// to k < m0+BM (used for P@V where P is strictly lower-triangular).
// Tiles: BM=BN=64, BK=16; block (16,16); each thread computes a 4x4 microtile.
// ---------------------------------------------------------------------------
template <bool ADD_BIAS>
__global__ __launch_bounds__(256)
void gemm_nn_kernel(const float* __restrict__ A, const float* __restrict__ Bm,
                    const float* __restrict__ bias, float* __restrict__ C,
                    int M, int N, int Kd,
                    long long sA, long long sB, long long sC,
                    int kLimitCausal)
{
    const int BM = 64, BN = 64, BK = 16;
    __shared__ float As[BK][BM + 4];   // As[k][m], row stride 68 (16B-aligned)
    __shared__ float Bs[BK][BN + 4];   // Bs[k][n]

    const int b = blockIdx.z;
    A += (long long)b * sA;
    Bm += (long long)b * sB;
    C += (long long)b * sC;

    const int m0 = blockIdx.y * BM;
    const int n0 = blockIdx.x * BN;
    const int tx = threadIdx.x, ty = threadIdx.y;
    const int t = ty * 16 + tx;

    // A-tile loader mapping: 64 rows x 16 cols, one float4 per thread
    const int ar = t >> 2, ac = (t & 3) * 4;
    // B-tile loader mapping: 16 rows x 64 cols
    const int br = t >> 4, bc = (t & 15) * 4;

    float acc[4][4] = {};

    int numK = Kd / BK;
    if (kLimitCausal) {
        int lim = (m0 + BM) / BK;    // P[i][k] == 0 for k > i
        if (lim < numK) numK = lim;
    }

    for (int kt = 0; kt < numK; ++kt) {
        const int k0 = kt * BK;
        float4 av = *(const float4*)&A[(long long)(m0 + ar) * Kd + k0 + ac];
        As[ac + 0][ar] = av.x;
        As[ac + 1][ar] = av.y;
        As[ac + 2][ar] = av.z;
        As[ac + 3][ar] = av.w;
        float4 bv = *(const float4*)&Bm[(long long)(k0 + br) * N + n0 + bc];
        *(float4*)&Bs[br][bc] = bv;
        __syncthreads();
#pragma unroll
        for (int kk = 0; kk < BK; ++kk) {
            float4 a4 = *(const float4*)&As[kk][ty * 4];
            float4 b4 = *(const float4*)&Bs[kk][tx * 4];
            float a[4] = {a4.x, a4.y, a4.z, a4.w};
            float bb[4] = {b4.x, b4.y, b4.z, b4.w};
#pragma unroll
            for (int i = 0; i < 4; ++i)
#pragma unroll
                for (int j = 0; j < 4; ++j)
                    acc[i][j] += a[i] * bb[j];
        }
        __syncthreads();
    }

#pragma unroll
    for (int i = 0; i < 4; ++i) {
        const int row = m0 + ty * 4 + i;
        const int col0 = n0 + tx * 4;
        float4 o;
        o.x = acc[i][0]; o.y = acc[i][1]; o.z = acc[i][2]; o.w = acc[i][3];
        if (ADD_BIAS) {
            float4 bsv = *(const float4*)&bias[col0];
            o.x += bsv.x; o.y += bsv.y; o.z += bsv.z; o.w += bsv.w;
        }
        *(float4*)&C[(long long)row * N + col0] = o;
    }
}

// ---------------------------------------------------------------------------
// S[b,i,j] = scale * dot(Q[b,i,:], K[b,j,:]) then masks applied IN REFERENCE
// ORDER and in fp32 arithmetic (to replicate the -1e9 quantization behavior):
//   s += NEG if j > i          (causal)
//   s += NEG if i>=len || j>=len  (length)
// Tiles fully above the diagonal skip the dot products entirely.
// ---------------------------------------------------------------------------
__global__ __launch_bounds__(256)
void scores_kernel(const float* __restrict__ Q, const float* __restrict__ Km,
                   const int* __restrict__ lengths, float* __restrict__ S,
                   int L, int Dd, float alpha)
{
    const int BM = 64, BN = 64, BK = 16;
    const int b = blockIdx.z;
    const float* Qb = Q + (long long)b * L * Dd;
    const float* Kb = Km + (long long)b * L * Dd;
    float* Sb = S + (long long)b * L * L;
    const int len = lengths[b];

    const int m0 = blockIdx.y * BM;
    const int n0 = blockIdx.x * BN;
    const int tx = threadIdx.x, ty = threadIdx.y;
    const int t = ty * 16 + tx;

    if (n0 >= m0 + BM) {
        // entire tile causally masked: value = fp32((S+NEG)[+NEG]) = NEG[+NEG]
#pragma unroll
        for (int i = 0; i < 4; ++i) {
            const int row = m0 + ty * 4 + i;
            const bool rinv = (row >= len);
#pragma unroll
            for (int j = 0; j < 4; ++j) {
                const int col = n0 + tx * 4 + j;
                float s = NEGV;
                if (rinv || col >= len) s += NEGV;
                Sb[(long long)row * L + col] = s;
            }
        }
        return;
    }

    __shared__ float As[BK][BM + 4];
    __shared__ float Ks[BK][BN + 4];
    const int ar = t >> 2, ac = (t & 3) * 4;

    float acc[4][4] = {};
    for (int k0 = 0; k0 < Dd; k0 += BK) {
        float4 av = *(const float4*)&Qb[(long long)(m0 + ar) * Dd + k0 + ac];
        As[ac + 0][ar] = av.x;
        As[ac + 1][ar] = av.y;
        As[ac + 2][ar] = av.z;
        As[ac + 3][ar] = av.w;
        float4 kv = *(const float4*)&Kb[(long long)(n0 + ar) * Dd + k0 + ac];
        Ks[ac + 0][ar] = kv.x;
        Ks[ac + 1][ar] = kv.y;
        Ks[ac + 2][ar] = kv.z;
        Ks[ac + 3][ar] = kv.w;
        __syncthreads();
#pragma unroll
        for (int kk = 0; kk < BK; ++kk) {
            float4 a4 = *(const float4*)&As[kk][ty * 4];
            float4 b4 = *(const float4*)&Ks[kk][tx * 4];
            float a[4] = {a4.x, a4.y, a4.z, a4.w};
            float bb[4] = {b4.x, b4.y, b4.z, b4.w};
#pragma unroll
            for (int i = 0; i < 4; ++i)
#pragma unroll
                for (int j = 0; j < 4; ++j)
                    acc[i][j] += a[i] * bb[j];
        }
        __syncthreads();
    }

#pragma unroll
    for (int i = 0; i < 4; ++i) {
        const int row = m0 + ty * 4 + i;
        const bool rinv = (row >= len);
#pragma unroll
        for (int j = 0; j < 4; ++j) {
            const int col = n0 + tx * 4 + j;
            float s = acc[i][j] * alpha;
            if (col > row) s += NEGV;            // causal first (ref order)
            if (rinv || col >= len) s += NEGV;   // then length mask
            Sb[(long long)row * L + col] = s;
        }
    }
}

// ---------------------------------------------------------------------------
// Row softmax in place. One block (256 threads) per row of length L=2048.
// ---------------------------------------------------------------------------
__global__ __launch_bounds__(256)
void softmax_kernel(float* __restrict__ S, int L)
{
    __shared__ float red[8];
    float* row = S + ((long long)blockIdx.y * L + blockIdx.x) * L;
    const int t = threadIdx.x;

    float vals[8];
    float m = -3.0e38f;
#pragma unroll
    for (int c = 0; c < 8; ++c) {
        float v = row[t + (c << 8)];
        vals[c] = v;
        m = fmaxf(m, v);
    }
#pragma unroll
    for (int off = 32; off > 0; off >>= 1) m = fmaxf(m, __shfl_down(m, off, 64));
    if ((t & 63) == 0) red[t >> 6] = m;
    __syncthreads();
    m = fmaxf(fmaxf(red[0], red[1]), fmaxf(red[2], red[3]));

    float s = 0.f;
#pragma unroll
    for (int c = 0; c < 8; ++c) {
        float e = __expf(vals[c] - m);
        vals[c] = e;
        s += e;
    }
#pragma unroll
    for (int off = 32; off > 0; off >>= 1) s += __shfl_down(s, off, 64);
    if ((t & 63) == 0) red[4 + (t >> 6)] = s;
    __syncthreads();
    s = red[4] + red[5] + red[6] + red[7];

    const float inv = 1.0f / s;
#pragma unroll
    for (int c = 0; c < 8; ++c) row[t + (c << 8)] = vals[c] * inv;
}

// ---------------------------------------------------------------------------
extern "C" void kernel_launch(void* const* d_in, const int* in_sizes, int n_in,
                              void* d_out, int out_size, void* d_ws, size_t ws_size,
                              hipStream_t stream)
{
    const float* x  = (const float*)d_in[0];
    const float* Wq = (const float*)d_in[1];
    const float* bq = (const float*)d_in[2];
    const float* Wk = (const float*)d_in[3];
    const float* bk = (const float*)d_in[4];
    const float* Wv = (const float*)d_in[5];
    const float* bv = (const float*)d_in[6];
    const int*  len = (const int*)d_in[7];
    float* out = (float*)d_out;

    const int B = 4, L = 2048, D = 1024;
    const int M = B * L;                 // 8192

    // Workspace layout (fp32): Q, K, V: M*D each; S: B*L*L.  Total 160 MB.
    float* Q  = (float*)d_ws;
    float* Kp = Q  + (size_t)M * D;
    float* V  = Kp + (size_t)M * D;
    float* S  = V  + (size_t)M * D;

    dim3 blk(16, 16);

    // 1) Q/K/V projections: [8192,1024] x [1024,1024] + bias
    dim3 g1(D / 64, M / 64, 1);
    gemm_nn_kernel<true><<<g1, blk, 0, stream>>>(x, Wq, bq, Q,  M, D, D, 0, 0, 0, 0);
    gemm_nn_kernel<true><<<g1, blk, 0, stream>>>(x, Wk, bk, Kp, M, D, D, 0, 0, 0, 0);
    gemm_nn_kernel<true><<<g1, blk, 0, stream>>>(x, Wv, bv, V,  M, D, D, 0, 0, 0, 0);

    // 2) S = scale * Q K^T + masks (batched over B)
    dim3 g2(L / 64, L / 64, B);
    scores_kernel<<<g2, blk, 0, stream>>>(Q, Kp, len, S, L, D, 0.03125f);

    // 3) softmax rows of S (in place)
    softmax_kernel<<<dim3(L, B), dim3(256), 0, stream>>>(S, L);

    // 4) out = P @ V (batched, causal k-limit since P is lower-triangular)
    dim3 g3(D / 64, L / 64, B);
    gemm_nn_kernel<false><<<g3, blk, 0, stream>>>(S, V, nullptr, out, L, D, L,
                                                  (long long)L * L,
                                                  (long long)L * D,
                                                  (long long)L * D, 1);
}

// Round 2
// 335.329 us; speedup vs baseline: 4.3350x; 4.3350x over previous
//
#include <hip/hip_runtime.h>

#define NEGV (-1.0e9f)

typedef __bf16 bf16_t;
typedef __bf16 bf16x8 __attribute__((ext_vector_type(8)));
typedef __bf16 bf16x4 __attribute__((ext_vector_type(4)));
typedef float  f32x4  __attribute__((ext_vector_type(4)));

// async global->LDS, 16B per lane; LDS dest is wave-uniform base + lane*16
__device__ __forceinline__ void gld16(const void* g, void* l) {
    __builtin_amdgcn_global_load_lds(
        (const __attribute__((address_space(1))) void*)g,
        (__attribute__((address_space(3))) void*)l, 16, 0, 0);
}

// ---------------------------------------------------------------------------
// NT MFMA mainloop: C[128,128] tile = A[128,K] x B[128,K]^T  (both row-major,
// k-contiguous). Block = 256 threads = 4 waves in 2x2; each wave owns 64x64 =
// 4x4 tiles of 16x16, mfma_f32_16x16x32_bf16. A,B already offset to tile base.
// ---------------------------------------------------------------------------
__device__ __forceinline__ void nt_mainloop(
    const bf16_t* __restrict__ A, const bf16_t* __restrict__ B,
    int ldA, int ldB, int numKsteps,
    bf16_t* Atile, bf16_t* Btile, int tid, f32x4 acc[4][4])
{
    const int w    = tid >> 6;
    const int lane = tid & 63;
    const int wm   = w & 1;
    const int wn   = w >> 1;
    const int srow = lane >> 2;          // staging row within 16-row chunk
    const int skc  = (lane & 3) * 8;     // staging k offset (elements)
    const int quad = lane >> 4;
    const int l16  = lane & 15;

    // each wave stages 2x16 rows of A and of B per K-step
    const bf16_t* ga0 = A + (size_t)((w * 2 + 0) * 16 + srow) * ldA + skc;
    const bf16_t* ga1 = A + (size_t)((w * 2 + 1) * 16 + srow) * ldA + skc;
    const bf16_t* gb0 = B + (size_t)((w * 2 + 0) * 16 + srow) * ldB + skc;
    const bf16_t* gb1 = B + (size_t)((w * 2 + 1) * 16 + srow) * ldB + skc;
    bf16_t* la0 = Atile + (w * 2 + 0) * 16 * 32;
    bf16_t* la1 = Atile + (w * 2 + 1) * 16 * 32;
    bf16_t* lb0 = Btile + (w * 2 + 0) * 16 * 32;
    bf16_t* lb1 = Btile + (w * 2 + 1) * 16 * 32;

    for (int kt = 0; kt < numKsteps; ++kt) {
        gld16(ga0, la0);
        gld16(ga1, la1);
        gld16(gb0, lb0);
        gld16(gb1, lb1);
        ga0 += 32; ga1 += 32; gb0 += 32; gb1 += 32;
        __syncthreads();

        bf16x8 af[4], bf[4];
#pragma unroll
        for (int i = 0; i < 4; ++i)
            af[i] = *(const bf16x8*)&Atile[(wm * 64 + i * 16 + l16) * 32 + quad * 8];
#pragma unroll
        for (int j = 0; j < 4; ++j)
            bf[j] = *(const bf16x8*)&Btile[(wn * 64 + j * 16 + l16) * 32 + quad * 8];
#pragma unroll
        for (int i = 0; i < 4; ++i)
#pragma unroll
            for (int j = 0; j < 4; ++j)
                acc[i][j] = __builtin_amdgcn_mfma_f32_16x16x32_bf16(af[i], bf[j], acc[i][j], 0, 0, 0);
        __syncthreads();
    }
}

// ---------------------------------------------------------------------------
// fp32 -> bf16 bulk convert (8 elems/thread)
// ---------------------------------------------------------------------------
__global__ __launch_bounds__(256)
void convert_x_kernel(const float* __restrict__ x, bf16_t* __restrict__ xb)
{
    const size_t i = ((size_t)blockIdx.x * 256 + threadIdx.x) * 8;
    float4 a = *(const float4*)&x[i];
    float4 b = *(const float4*)&x[i + 4];
    bf16x8 o;
    o[0] = (bf16_t)a.x; o[1] = (bf16_t)a.y; o[2] = (bf16_t)a.z; o[3] = (bf16_t)a.w;
    o[4] = (bf16_t)b.x; o[5] = (bf16_t)b.y; o[6] = (bf16_t)b.z; o[7] = (bf16_t)b.w;
    *(bf16x8*)&xb[i] = o;
}

// ---------------------------------------------------------------------------
// W [1024x1024] fp32 -> WT [1024x1024] bf16 (transposed), 32x32 LDS tiles
// ---------------------------------------------------------------------------
__global__ __launch_bounds__(256)
void transpose_w_kernel(const float* __restrict__ W, bf16_t* __restrict__ WT)
{
    __shared__ float t[32][33];
    const int k0 = blockIdx.y * 32, n0 = blockIdx.x * 32;
    const int r = threadIdx.x >> 3, c4 = (threadIdx.x & 7) * 4;
    float4 v = *(const float4*)&W[(size_t)(k0 + r) * 1024 + n0 + c4];
    t[r][c4 + 0] = v.x; t[r][c4 + 1] = v.y; t[r][c4 + 2] = v.z; t[r][c4 + 3] = v.w;
    __syncthreads();
    bf16x4 o;
#pragma unroll
    for (int j = 0; j < 4; ++j) o[j] = (bf16_t)t[c4 + j][r];
    *(bf16x4*)&WT[(size_t)(n0 + r) * 1024 + k0 + c4] = o;
}

// ---------------------------------------------------------------------------
// V [B][L][D] bf16 -> VT [B][D][L] bf16, 32x32 tiles
// ---------------------------------------------------------------------------
__global__ __launch_bounds__(256)
void transpose_v_kernel(const bf16_t* __restrict__ V, bf16_t* __restrict__ VT,
                        int L, int Dd)
{
    __shared__ bf16_t t[32][34];
    const int b = blockIdx.z;
    const int l0 = blockIdx.x * 32, d0 = blockIdx.y * 32;
    const bf16_t* Vb = V + (size_t)b * L * Dd;
    bf16_t* VTb = VT + (size_t)b * Dd * L;
    const int r = threadIdx.x >> 3, c4 = (threadIdx.x & 7) * 4;
    bf16x4 v = *(const bf16x4*)&Vb[(size_t)(l0 + r) * Dd + d0 + c4];
#pragma unroll
    for (int j = 0; j < 4; ++j) t[r][c4 + j] = v[j];
    __syncthreads();
    bf16x4 o;
#pragma unroll
    for (int j = 0; j < 4; ++j) o[j] = t[c4 + j][r];
    *(bf16x4*)&VTb[(size_t)(d0 + r) * L + l0 + c4] = o;
}

// ---------------------------------------------------------------------------
// Projection: C[M,N] bf16 = A[M,K] x BT[N,K]^T + bias
// ---------------------------------------------------------------------------
__global__ __launch_bounds__(256)
void gemm_proj_kernel(const bf16_t* __restrict__ A, const bf16_t* __restrict__ Bt,
                      const float* __restrict__ bias, bf16_t* __restrict__ C,
                      int N, int Kd)
{
    __shared__ bf16_t Atile[128 * 32];
    __shared__ bf16_t Btile[128 * 32];
    const int tid = threadIdx.x;
    const int m0 = blockIdx.y * 128, n0 = blockIdx.x * 128;

    f32x4 acc[4][4];
#pragma unroll
    for (int i = 0; i < 4; ++i)
#pragma unroll
        for (int j = 0; j < 4; ++j) acc[i][j] = (f32x4)(0.0f);

    nt_mainloop(A + (size_t)m0 * Kd, Bt + (size_t)n0 * Kd, Kd, Kd, Kd / 32,
                Atile, Btile, tid, acc);

    const int w = tid >> 6, lane = tid & 63;
    const int wm = w & 1, wn = w >> 1, quad = lane >> 4, l16 = lane & 15;
#pragma unroll
    for (int j = 0; j < 4; ++j) {
        const int col = n0 + wn * 64 + j * 16 + l16;
        const float bv = bias[col];
#pragma unroll
        for (int i = 0; i < 4; ++i) {
#pragma unroll
            for (int r = 0; r < 4; ++r) {
                const int row = m0 + wm * 64 + i * 16 + quad * 4 + r;
                C[(size_t)row * N + col] = (bf16_t)(acc[i][j][r] + bv);
            }
        }
    }
}

// ---------------------------------------------------------------------------
// Scores: S[b] fp32 = alpha * Q[b] K[b]^T with masks fused (reference order).
// Tiles fully above the diagonal skip the GEMM and write constants.
// ---------------------------------------------------------------------------
__global__ __launch_bounds__(256)
void scores_mfma_kernel(const bf16_t* __restrict__ Q, const bf16_t* __restrict__ K,
                        const int* __restrict__ lengths, float* __restrict__ S,
                        int L, int Dd, float alpha)
{
    const int b = blockIdx.z;
    const int len = lengths[b];
    const int m0 = blockIdx.y * 128, n0 = blockIdx.x * 128;
    float* Sb = S + (size_t)b * L * L;
    const int tid = threadIdx.x;

    if (n0 >= m0 + 128) {   // fully causally masked tile
#pragma unroll
        for (int p = 0; p < 16; ++p) {
            const int idx = p * 256 + tid;       // float4 slot
            const int row = m0 + (idx >> 5);
            const int col0 = n0 + (idx & 31) * 4;
            const bool rinv = (row >= len);
            float4 o;
            o.x = NEGV + ((rinv || col0 + 0 >= len) ? NEGV : 0.f);
            o.y = NEGV + ((rinv || col0 + 1 >= len) ? NEGV : 0.f);
            o.z = NEGV + ((rinv || col0 + 2 >= len) ? NEGV : 0.f);
            o.w = NEGV + ((rinv || col0 + 3 >= len) ? NEGV : 0.f);
            *(float4*)&Sb[(size_t)row * L + col0] = o;
        }
        return;
    }

    __shared__ bf16_t Atile[128 * 32];
    __shared__ bf16_t Btile[128 * 32];
    f32x4 acc[4][4];
#pragma unroll
    for (int i = 0; i < 4; ++i)
#pragma unroll
        for (int j = 0; j < 4; ++j) acc[i][j] = (f32x4)(0.0f);

    const bf16_t* Qb = Q + (size_t)b * L * Dd + (size_t)m0 * Dd;
    const bf16_t* Kb = K + (size_t)b * L * Dd + (size_t)n0 * Dd;
    nt_mainloop(Qb, Kb, Dd, Dd, Dd / 32, Atile, Btile, tid, acc);

    const int w = tid >> 6, lane = tid & 63;
    const int wm = w & 1, wn = w >> 1, quad = lane >> 4, l16 = lane & 15;
#pragma unroll
    for (int i = 0; i < 4; ++i) {
#pragma unroll
        for (int j = 0; j < 4; ++j) {
            const int col = n0 + wn * 64 + j * 16 + l16;
#pragma unroll
            for (int r = 0; r < 4; ++r) {
                const int row = m0 + wm * 64 + i * 16 + quad * 4 + r;
                float s = acc[i][j][r] * alpha;
                if (col > row) s += NEGV;                 // causal first
                if (row >= len || col >= len) s += NEGV;  // then length mask
                Sb[(size_t)row * L + col] = s;
            }
        }
    }
}

// ---------------------------------------------------------------------------
// Row softmax: S fp32 [B*L rows of L] -> P bf16
// ---------------------------------------------------------------------------
__global__ __launch_bounds__(256)
void softmax_kernel(const float* __restrict__ S, bf16_t* __restrict__ P, int L)
{
    __shared__ float red[8];
    const size_t rowi = (size_t)blockIdx.y * L + blockIdx.x;
    const float* row = S + rowi * L;
    bf16_t* prow = P + rowi * L;
    const int t = threadIdx.x;
    const int w = t >> 6, lane = t & 63;

    float v[8];
    float4 a = *(const float4*)&row[t * 8];
    float4 b = *(const float4*)&row[t * 8 + 4];
    v[0] = a.x; v[1] = a.y; v[2] = a.z; v[3] = a.w;
    v[4] = b.x; v[5] = b.y; v[6] = b.z; v[7] = b.w;

    float m = v[0];
#pragma unroll
    for (int j = 1; j < 8; ++j) m = fmaxf(m, v[j]);
#pragma unroll
    for (int off = 32; off > 0; off >>= 1) m = fmaxf(m, __shfl_down(m, off, 64));
    if (lane == 0) red[w] = m;
    __syncthreads();
    m = fmaxf(fmaxf(red[0], red[1]), fmaxf(red[2], red[3]));

    float s = 0.f;
#pragma unroll
    for (int j = 0; j < 8; ++j) {
        v[j] = __expf(v[j] - m);
        s += v[j];
    }
#pragma unroll
    for (int off = 32; off > 0; off >>= 1) s += __shfl_down(s, off, 64);
    if (lane == 0) red[4 + w] = s;
    __syncthreads();
    s = red[4] + red[5] + red[6] + red[7];

    const float inv = 1.0f / s;
    bf16x8 o;
#pragma unroll
    for (int j = 0; j < 8; ++j) o[j] = (bf16_t)(v[j] * inv);
    *(bf16x8*)&prow[t * 8] = o;
}

// ---------------------------------------------------------------------------
// PV: O[b] fp32 [L,D] = P[b][L,L] x VT[b][D,L]^T, causal k-limit
// ---------------------------------------------------------------------------
__global__ __launch_bounds__(256)
void pv_mfma_kernel(const bf16_t* __restrict__ P, const bf16_t* __restrict__ VT,
                    float* __restrict__ O, int L, int Dd)
{
    __shared__ bf16_t Atile[128 * 32];
    __shared__ bf16_t Btile[128 * 32];
    const int b = blockIdx.z;
    const int m0 = blockIdx.y * 128, n0 = blockIdx.x * 128;
    const int tid = threadIdx.x;

    f32x4 acc[4][4];
#pragma unroll
    for (int i = 0; i < 4; ++i)
#pragma unroll
        for (int j = 0; j < 4; ++j) acc[i][j] = (f32x4)(0.0f);

    const int ksteps = (m0 + 128) / 32;   // P is zero for j > i
    const bf16_t* Pb = P + (size_t)b * L * L + (size_t)m0 * L;
    const bf16_t* Vb = VT + (size_t)b * Dd * L + (size_t)n0 * L;
    nt_mainloop(Pb, Vb, L, L, ksteps, Atile, Btile, tid, acc);

    float* Ob = O + (size_t)b * L * Dd;
    const int w = tid >> 6, lane = tid & 63;
    const int wm = w & 1, wn = w >> 1, quad = lane >> 4, l16 = lane & 15;
#pragma unroll
    for (int i = 0; i < 4; ++i) {
#pragma unroll
        for (int j = 0; j < 4; ++j) {
            const int col = n0 + wn * 64 + j * 16 + l16;
#pragma unroll
            for (int r = 0; r < 4; ++r) {
                const int row = m0 + wm * 64 + i * 16 + quad * 4 + r;
                Ob[(size_t)row * Dd + col] = acc[i][j][r];
            }
        }
    }
}

// ---------------------------------------------------------------------------
extern "C" void kernel_launch(void* const* d_in, const int* in_sizes, int n_in,
                              void* d_out, int out_size, void* d_ws, size_t ws_size,
                              hipStream_t stream)
{
    const float* x  = (const float*)d_in[0];
    const float* Wq = (const float*)d_in[1];
    const float* bq = (const float*)d_in[2];
    const float* Wk = (const float*)d_in[3];
    const float* bk = (const float*)d_in[4];
    const float* Wv = (const float*)d_in[5];
    const float* bv = (const float*)d_in[6];
    const int*  len = (const int*)d_in[7];
    float* out = (float*)d_out;

    const int B = 4, L = 2048, D = 1024;
    const int M = B * L;   // 8192

    // Workspace layout (134 MB total):
    bf16_t* xb  = (bf16_t*)d_ws;            // 16 MB  (reused as VT later)
    bf16_t* WTq = xb + (size_t)M * D;       // 2 MB
    bf16_t* WTk = WTq + (size_t)D * D;      // 2 MB
    bf16_t* WTv = WTk + (size_t)D * D;      // 2 MB
    bf16_t* Qb  = WTv + (size_t)D * D;      // 16 MB  (reused as P[0:16MB])
    bf16_t* Kb  = Qb + (size_t)M * D;       // 16 MB  (reused as P[16:32MB])
    bf16_t* Vb  = Kb + (size_t)M * D;       // 16 MB
    float*  S   = (float*)(Vb + (size_t)M * D);  // 64 MB fp32
    bf16_t* VT  = xb;                       // alias: xb dead after projections
    bf16_t* P   = Qb;                       // alias: Qb/Kb dead after scores

    // 1) x -> bf16
    convert_x_kernel<<<(M * D) / (256 * 8), 256, 0, stream>>>(x, xb);

    // 2) W transposes -> bf16
    dim3 gt(32, 32);
    transpose_w_kernel<<<gt, 256, 0, stream>>>(Wq, WTq);
    transpose_w_kernel<<<gt, 256, 0, stream>>>(Wk, WTk);
    transpose_w_kernel<<<gt, 256, 0, stream>>>(Wv, WTv);

    // 3) projections (NT): Qb/Kb/Vb bf16 [M][D]
    dim3 gp(D / 128, M / 128);
    gemm_proj_kernel<<<gp, 256, 0, stream>>>(xb, WTq, bq, Qb, D, D);
    gemm_proj_kernel<<<gp, 256, 0, stream>>>(xb, WTk, bk, Kb, D, D);
    gemm_proj_kernel<<<gp, 256, 0, stream>>>(xb, WTv, bv, Vb, D, D);

    // 4) V transpose (into dead xb region)
    transpose_v_kernel<<<dim3(L / 32, D / 32, B), 256, 0, stream>>>(Vb, VT, L, D);

    // 5) scores with fused masks
    scores_mfma_kernel<<<dim3(L / 128, L / 128, B), 256, 0, stream>>>(
        Qb, Kb, len, S, L, D, 0.03125f);

    // 6) softmax -> P bf16 (into dead Qb/Kb region)
    softmax_kernel<<<dim3(L, B), 256, 0, stream>>>(S, P, L);

    // 7) O = P @ V (causal k-limit)
    pv_mfma_kernel<<<dim3(D / 128, L / 128, B), 256, 0, stream>>>(P, VT, out, L, D);
}

// Round 3
// 305.764 us; speedup vs baseline: 4.7542x; 1.0967x over previous
//
#include <hip/hip_runtime.h>

#define NEGV (-1.0e9f)

typedef __bf16 bf16_t;
typedef __bf16 bf16x8 __attribute__((ext_vector_type(8)));
typedef __bf16 bf16x4 __attribute__((ext_vector_type(4)));
typedef float  f32x4  __attribute__((ext_vector_type(4)));

// async global->LDS, 16B per lane; LDS dest is wave-uniform base + lane*16
__device__ __forceinline__ void gld16(const void* g, void* l) {
    __builtin_amdgcn_global_load_lds(
        (const __attribute__((address_space(1))) void*)g,
        (__attribute__((address_space(3))) void*)l, 16, 0, 0);
}

// ---------------------------------------------------------------------------
// NT MFMA mainloop: C[128,128] tile = A[128,K] x B[128,K]^T  (both row-major,
// k-contiguous, arbitrary row strides). 256 threads = 4 waves in 2x2; each
// wave owns 64x64 via 4x4 tiles of mfma_f32_16x16x32_bf16.
// ---------------------------------------------------------------------------
__device__ __forceinline__ void nt_mainloop(
    const bf16_t* __restrict__ A, const bf16_t* __restrict__ B,
    int ldA, int ldB, int numKsteps,
    bf16_t* Atile, bf16_t* Btile, int tid, f32x4 acc[4][4])
{
    const int w    = tid >> 6;
    const int lane = tid & 63;
    const int wm   = w & 1;
    const int wn   = w >> 1;
    const int srow = lane >> 2;          // staging row within 16-row chunk
    const int skc  = (lane & 3) * 8;     // staging k offset (elements)
    const int quad = lane >> 4;
    const int l16  = lane & 15;

    const bf16_t* ga0 = A + (size_t)((w * 2 + 0) * 16 + srow) * ldA + skc;
    const bf16_t* ga1 = A + (size_t)((w * 2 + 1) * 16 + srow) * ldA + skc;
    const bf16_t* gb0 = B + (size_t)((w * 2 + 0) * 16 + srow) * ldB + skc;
    const bf16_t* gb1 = B + (size_t)((w * 2 + 1) * 16 + srow) * ldB + skc;
    bf16_t* la0 = Atile + (w * 2 + 0) * 16 * 32;
    bf16_t* la1 = Atile + (w * 2 + 1) * 16 * 32;
    bf16_t* lb0 = Btile + (w * 2 + 0) * 16 * 32;
    bf16_t* lb1 = Btile + (w * 2 + 1) * 16 * 32;

    for (int kt = 0; kt < numKsteps; ++kt) {
        gld16(ga0, la0);
        gld16(ga1, la1);
        gld16(gb0, lb0);
        gld16(gb1, lb1);
        ga0 += 32; ga1 += 32; gb0 += 32; gb1 += 32;
        __syncthreads();

        bf16x8 af[4], bfr[4];
#pragma unroll
        for (int i = 0; i < 4; ++i)
            af[i] = *(const bf16x8*)&Atile[(wm * 64 + i * 16 + l16) * 32 + quad * 8];
#pragma unroll
        for (int j = 0; j < 4; ++j)
            bfr[j] = *(const bf16x8*)&Btile[(wn * 64 + j * 16 + l16) * 32 + quad * 8];
#pragma unroll
        for (int i = 0; i < 4; ++i)
#pragma unroll
            for (int j = 0; j < 4; ++j)
                acc[i][j] = __builtin_amdgcn_mfma_f32_16x16x32_bf16(af[i], bfr[j], acc[i][j], 0, 0, 0);
        __syncthreads();
    }
}

// ---------------------------------------------------------------------------
__global__ __launch_bounds__(256)
void convert_x_kernel(const float* __restrict__ x, bf16_t* __restrict__ xb)
{
    const size_t i = ((size_t)blockIdx.x * 256 + threadIdx.x) * 8;
    float4 a = *(const float4*)&x[i];
    float4 b = *(const float4*)&x[i + 4];
    bf16x8 o;
    o[0] = (bf16_t)a.x; o[1] = (bf16_t)a.y; o[2] = (bf16_t)a.z; o[3] = (bf16_t)a.w;
    o[4] = (bf16_t)b.x; o[5] = (bf16_t)b.y; o[6] = (bf16_t)b.z; o[7] = (bf16_t)b.w;
    *(bf16x8*)&xb[i] = o;
}

// W [1024x1024] fp32 -> WT [1024x1024] bf16 transposed
__global__ __launch_bounds__(256)
void transpose_w_kernel(const float* __restrict__ W, bf16_t* __restrict__ WT)
{
    __shared__ float t[32][33];
    const int k0 = blockIdx.y * 32, n0 = blockIdx.x * 32;
    const int r = threadIdx.x >> 3, c4 = (threadIdx.x & 7) * 4;
    float4 v = *(const float4*)&W[(size_t)(k0 + r) * 1024 + n0 + c4];
    t[r][c4 + 0] = v.x; t[r][c4 + 1] = v.y; t[r][c4 + 2] = v.z; t[r][c4 + 3] = v.w;
    __syncthreads();
    bf16x4 o;
#pragma unroll
    for (int j = 0; j < 4; ++j) o[j] = (bf16_t)t[c4 + j][r];
    *(bf16x4*)&WT[(size_t)(n0 + r) * 1024 + k0 + c4] = o;
}

// V (ldv-strided rows) -> VT [B][D][L]
__global__ __launch_bounds__(256)
void transpose_v_kernel(const bf16_t* __restrict__ V, bf16_t* __restrict__ VT,
                        int L, int Dd, int ldv)
{
    __shared__ bf16_t t[32][34];
    const int b = blockIdx.z;
    const int l0 = blockIdx.x * 32, d0 = blockIdx.y * 32;
    const bf16_t* Vb = V + (size_t)b * L * ldv;
    bf16_t* VTb = VT + (size_t)b * Dd * L;
    const int r = threadIdx.x >> 3, c4 = (threadIdx.x & 7) * 4;
    bf16x4 v = *(const bf16x4*)&Vb[(size_t)(l0 + r) * ldv + d0 + c4];
#pragma unroll
    for (int j = 0; j < 4; ++j) t[r][c4 + j] = v[j];
    __syncthreads();
    bf16x4 o;
#pragma unroll
    for (int j = 0; j < 4; ++j) o[j] = t[c4 + j][r];
    *(bf16x4*)&VTb[(size_t)(d0 + r) * L + l0 + c4] = o;
}

// ---------------------------------------------------------------------------
// Fused QKV projection: C[M,3072] bf16 = A[M,1024] x WT[3072,1024]^T + bias
// ---------------------------------------------------------------------------
__global__ __launch_bounds__(256)
void gemm_qkv_kernel(const bf16_t* __restrict__ A, const bf16_t* __restrict__ Bt,
                     const float* __restrict__ bq, const float* __restrict__ bk,
                     const float* __restrict__ bv, bf16_t* __restrict__ C,
                     int N, int Kd)
{
    __shared__ bf16_t Atile[128 * 32];
    __shared__ bf16_t Btile[128 * 32];
    const int tid = threadIdx.x;
    const int m0 = blockIdx.y * 128, n0 = blockIdx.x * 128;

    f32x4 acc[4][4];
#pragma unroll
    for (int i = 0; i < 4; ++i)
#pragma unroll
        for (int j = 0; j < 4; ++j) acc[i][j] = (f32x4)(0.0f);

    nt_mainloop(A + (size_t)m0 * Kd, Bt + (size_t)n0 * Kd, Kd, Kd, Kd / 32,
                Atile, Btile, tid, acc);

    const int w = tid >> 6, lane = tid & 63;
    const int wm = w & 1, wn = w >> 1, quad = lane >> 4, l16 = lane & 15;
#pragma unroll
    for (int j = 0; j < 4; ++j) {
        const int col = n0 + wn * 64 + j * 16 + l16;
        const float* bp = (col < 1024) ? bq : (col < 2048) ? bk : bv;
        const float bval = bp[col & 1023];
#pragma unroll
        for (int i = 0; i < 4; ++i) {
#pragma unroll
            for (int r = 0; r < 4; ++r) {
                const int row = m0 + wm * 64 + i * 16 + quad * 4 + r;
                C[(size_t)row * N + col] = (bf16_t)(acc[i][j][r] + bval);
            }
        }
    }
}

// ---------------------------------------------------------------------------
// Scores, triangular-only launch: blockIdx.x in [0,136) -> (it,jt), jt<=it.
// S fp32 written only for lower-triangular tiles; masks in reference order.
// ---------------------------------------------------------------------------
__global__ __launch_bounds__(256)
void scores_mfma_kernel(const bf16_t* __restrict__ Q, const bf16_t* __restrict__ K,
                        int ldq, const int* __restrict__ lengths,
                        float* __restrict__ S, int L, int Dd, float alpha)
{
    const int b = blockIdx.z;
    const int len = lengths[b];
    int it = (int)((sqrtf(8.0f * blockIdx.x + 1.0f) - 1.0f) * 0.5f);
    while ((it + 1) * (it + 2) / 2 <= (int)blockIdx.x) ++it;
    while (it * (it + 1) / 2 > (int)blockIdx.x) --it;
    const int jt = blockIdx.x - it * (it + 1) / 2;
    const int m0 = it * 128, n0 = jt * 128;
    float* Sb = S + (size_t)b * L * L;
    const int tid = threadIdx.x;

    __shared__ bf16_t Atile[128 * 32];
    __shared__ bf16_t Btile[128 * 32];
    f32x4 acc[4][4];
#pragma unroll
    for (int i = 0; i < 4; ++i)
#pragma unroll
        for (int j = 0; j < 4; ++j) acc[i][j] = (f32x4)(0.0f);

    const bf16_t* Qb = Q + (size_t)b * L * ldq + (size_t)m0 * ldq;
    const bf16_t* Kb = K + (size_t)b * L * ldq + (size_t)n0 * ldq;
    nt_mainloop(Qb, Kb, ldq, ldq, Dd / 32, Atile, Btile, tid, acc);

    const int w = tid >> 6, lane = tid & 63;
    const int wm = w & 1, wn = w >> 1, quad = lane >> 4, l16 = lane & 15;
#pragma unroll
    for (int i = 0; i < 4; ++i) {
#pragma unroll
        for (int j = 0; j < 4; ++j) {
            const int col = n0 + wn * 64 + j * 16 + l16;
#pragma unroll
            for (int r = 0; r < 4; ++r) {
                const int row = m0 + wm * 64 + i * 16 + quad * 4 + r;
                float s = acc[i][j][r] * alpha;
                if (col > row) s += NEGV;                 // causal first
                if (row >= len || col >= len) s += NEGV;  // then length mask
                Sb[(size_t)row * L + col] = s;
            }
        }
    }
}

// ---------------------------------------------------------------------------
// Row softmax, causally bounded: reads S[0,bound), writes P[0,bound) bf16
// where bound = round_up(i+1, 128). PV never reads beyond bound.
// ---------------------------------------------------------------------------
__global__ __launch_bounds__(256)
void softmax_kernel(const float* __restrict__ S, bf16_t* __restrict__ P,
                    int L, int ldp)
{
    __shared__ float red[8];
    const int i = blockIdx.x;
    const int bound = ((i >> 7) + 1) << 7;
    const float* row = S + ((size_t)blockIdx.y * L + i) * L;
    bf16_t* prow = P + ((size_t)blockIdx.y * L + i) * ldp;
    const int t = threadIdx.x;
    const int w = t >> 6, lane = t & 63;
    const int j8 = t * 8;
    const bool act = j8 < bound;

    float v[8];
    float m = -3.0e38f;
    if (act) {
        float4 a = *(const float4*)&row[j8];
        float4 b = *(const float4*)&row[j8 + 4];
        v[0] = a.x; v[1] = a.y; v[2] = a.z; v[3] = a.w;
        v[4] = b.x; v[5] = b.y; v[6] = b.z; v[7] = b.w;
#pragma unroll
        for (int j = 0; j < 8; ++j) m = fmaxf(m, v[j]);
    }
#pragma unroll
    for (int off = 32; off > 0; off >>= 1) m = fmaxf(m, __shfl_down(m, off, 64));
    if (lane == 0) red[w] = m;
    __syncthreads();
    m = fmaxf(fmaxf(red[0], red[1]), fmaxf(red[2], red[3]));

    float s = 0.f;
    if (act) {
#pragma unroll
        for (int j = 0; j < 8; ++j) {
            v[j] = __expf(v[j] - m);
            s += v[j];
        }
    }
#pragma unroll
    for (int off = 32; off > 0; off >>= 1) s += __shfl_down(s, off, 64);
    if (lane == 0) red[4 + w] = s;
    __syncthreads();
    s = red[4] + red[5] + red[6] + red[7];

    if (act) {
        const float inv = 1.0f / s;
        bf16x8 o;
#pragma unroll
        for (int j = 0; j < 8; ++j) o[j] = (bf16_t)(v[j] * inv);
        *(bf16x8*)&prow[j8] = o;
    }
}

// ---------------------------------------------------------------------------
// PV: O[b][L,D] fp32 = P[b][L,L] x VT[b][D,L]^T, causal k-limit, heavy-first
// ---------------------------------------------------------------------------
__global__ __launch_bounds__(256)
void pv_mfma_kernel(const bf16_t* __restrict__ P, int ldp,
                    const bf16_t* __restrict__ VT,
                    float* __restrict__ O, int L, int Dd)
{
    __shared__ bf16_t Atile[128 * 32];
    __shared__ bf16_t Btile[128 * 32];
    const int b = blockIdx.z;
    const int mt = gridDim.y - 1 - blockIdx.y;   // heavy tiles dispatch first
    const int m0 = mt * 128, n0 = blockIdx.x * 128;
    const int tid = threadIdx.x;

    f32x4 acc[4][4];
#pragma unroll
    for (int i = 0; i < 4; ++i)
#pragma unroll
        for (int j = 0; j < 4; ++j) acc[i][j] = (f32x4)(0.0f);

    const int ksteps = (m0 + 128) / 32;   // P[i][j]==0 for j>i
    const bf16_t* Pb = P + (size_t)b * L * ldp + (size_t)m0 * ldp;
    const bf16_t* Vb = VT + (size_t)b * Dd * L + (size_t)n0 * L;
    nt_mainloop(Pb, Vb, ldp, L, ksteps, Atile, Btile, tid, acc);

    float* Ob = O + (size_t)b * L * Dd;
    const int w = tid >> 6, lane = tid & 63;
    const int wm = w & 1, wn = w >> 1, quad = lane >> 4, l16 = lane & 15;
#pragma unroll
    for (int i = 0; i < 4; ++i) {
#pragma unroll
        for (int j = 0; j < 4; ++j) {
            const int col = n0 + wn * 64 + j * 16 + l16;
#pragma unroll
            for (int r = 0; r < 4; ++r) {
                const int row = m0 + wm * 64 + i * 16 + quad * 4 + r;
                Ob[(size_t)row * Dd + col] = acc[i][j][r];
            }
        }
    }
}

// ---------------------------------------------------------------------------
extern "C" void kernel_launch(void* const* d_in, const int* in_sizes, int n_in,
                              void* d_out, int out_size, void* d_ws, size_t ws_size,
                              hipStream_t stream)
{
    const float* x  = (const float*)d_in[0];
    const float* Wq = (const float*)d_in[1];
    const float* bq = (const float*)d_in[2];
    const float* Wk = (const float*)d_in[3];
    const float* bk = (const float*)d_in[4];
    const float* Wv = (const float*)d_in[5];
    const float* bv = (const float*)d_in[6];
    const int*  len = (const int*)d_in[7];
    float* out = (float*)d_out;

    const int B = 4, L = 2048, D = 1024;
    const int M = B * L;     // 8192
    const int N3 = 3 * D;    // 3072

    // Workspace (134 MB):
    //  xb  [M][1024] bf16 = 16 MB   (reused as VT [B][D][L] after projections)
    //  WT  [3072][1024] bf16 = 6 MB (Wq^T | Wk^T | Wv^T)
    //  QKV [M][3072] bf16 = 48 MB   (cols 0:Q 1024:K 2048:V; rows reused as P)
    //  S   [B][L][L] fp32 = 64 MB   (lower-triangular tiles only)
    bf16_t* xb  = (bf16_t*)d_ws;
    bf16_t* WT  = xb + (size_t)M * D;
    bf16_t* QKV = WT + (size_t)N3 * D;
    float*  S   = (float*)(QKV + (size_t)M * N3);
    bf16_t* VT  = xb;        // alias (xb dead after projections)
    bf16_t* P   = QKV;       // alias (Q,K cols dead after scores), ld = 3072

    // 1) x -> bf16
    convert_x_kernel<<<(M * D) / 2048, 256, 0, stream>>>(x, xb);

    // 2) W transposes into WT sections
    dim3 gt(32, 32);
    transpose_w_kernel<<<gt, 256, 0, stream>>>(Wq, WT);
    transpose_w_kernel<<<gt, 256, 0, stream>>>(Wk, WT + (size_t)D * D);
    transpose_w_kernel<<<gt, 256, 0, stream>>>(Wv, WT + (size_t)2 * D * D);

    // 3) fused QKV projection
    gemm_qkv_kernel<<<dim3(N3 / 128, M / 128), 256, 0, stream>>>(
        xb, WT, bq, bk, bv, QKV, N3, D);

    // 4) V transpose (V = QKV cols [2048,3072)) into dead xb
    transpose_v_kernel<<<dim3(L / 32, D / 32, B), 256, 0, stream>>>(
        QKV + 2048, VT, L, D, N3);

    // 5) scores, triangular tiles only
    scores_mfma_kernel<<<dim3(136, 1, B), 256, 0, stream>>>(
        QKV, QKV + 1024, N3, len, S, L, D, 0.03125f);

    // 6) bounded softmax -> P (aliased into QKV rows, cols [0,2048))
    softmax_kernel<<<dim3(L, B), 256, 0, stream>>>(S, P, L, N3);

    // 7) O = P @ V, causal k-limit, heavy tiles first
    pv_mfma_kernel<<<dim3(D / 128, L / 128, B), 256, 0, stream>>>(
        P, N3, VT, out, L, D);
}

// Round 4
// 303.627 us; speedup vs baseline: 4.7876x; 1.0070x over previous
//
#include <hip/hip_runtime.h>

#define NEGV (-1.0e9f)

typedef __bf16 bf16_t;
typedef __bf16 bf16x8 __attribute__((ext_vector_type(8)));
typedef __bf16 bf16x4 __attribute__((ext_vector_type(4)));
typedef float  f32x4  __attribute__((ext_vector_type(4)));

// async global->LDS, 16B per lane; LDS dest is wave-uniform base + lane*16
__device__ __forceinline__ void gld16(const void* g, void* l) {
    __builtin_amdgcn_global_load_lds(
        (const __attribute__((address_space(1))) void*)g,
        (__attribute__((address_space(3))) void*)l, 16, 0, 0);
}

// ---------------------------------------------------------------------------
// NT MFMA mainloop: C[128,128] tile = A[128,K] x B[128,K]^T  (both row-major,
// k-contiguous, arbitrary row strides). 256 threads = 4 waves in 2x2; each
// wave owns 64x64 via 4x4 tiles of mfma_f32_16x16x32_bf16.
//
// LDS layout is XOR-swizzled to kill the 8-way ds_read_b128 bank conflict:
// k-chunk c (16B) of row r lives at slot c ^ ((r>>1)&3). The swizzle is
// applied on the GLOBAL side during staging (lane l fetches chunk
// (l&3)^((l>>3)&3) of its row -- same 64B segment, still coalesced), since
// global_load_lds requires the linear base+lane*16 LDS destination.
// ---------------------------------------------------------------------------
__device__ __forceinline__ void nt_mainloop(
    const bf16_t* __restrict__ A, const bf16_t* __restrict__ B,
    int ldA, int ldB, int numKsteps,
    bf16_t* Atile, bf16_t* Btile, int tid, f32x4 acc[4][4])
{
    const int w    = tid >> 6;
    const int lane = tid & 63;
    const int wm   = w & 1;
    const int wn   = w >> 1;
    const int srow = lane >> 2;                                  // row in chunk
    const int skc  = ((lane & 3) ^ ((lane >> 3) & 3)) * 8;       // swizzled k
    const int quad = lane >> 4;
    const int l16  = lane & 15;
    const int sw   = (l16 >> 1) & 3;                             // read swizzle

    const bf16_t* ga0 = A + (size_t)((w * 2 + 0) * 16 + srow) * ldA + skc;
    const bf16_t* ga1 = A + (size_t)((w * 2 + 1) * 16 + srow) * ldA + skc;
    const bf16_t* gb0 = B + (size_t)((w * 2 + 0) * 16 + srow) * ldB + skc;
    const bf16_t* gb1 = B + (size_t)((w * 2 + 1) * 16 + srow) * ldB + skc;
    bf16_t* la0 = Atile + (w * 2 + 0) * 16 * 32;
    bf16_t* la1 = Atile + (w * 2 + 1) * 16 * 32;
    bf16_t* lb0 = Btile + (w * 2 + 0) * 16 * 32;
    bf16_t* lb1 = Btile + (w * 2 + 1) * 16 * 32;

    for (int kt = 0; kt < numKsteps; ++kt) {
        gld16(ga0, la0);
        gld16(ga1, la1);
        gld16(gb0, lb0);
        gld16(gb1, lb1);
        ga0 += 32; ga1 += 32; gb0 += 32; gb1 += 32;
        __syncthreads();

        bf16x8 af[4], bfr[4];
#pragma unroll
        for (int i = 0; i < 4; ++i)
            af[i] = *(const bf16x8*)&Atile[(wm * 64 + i * 16 + l16) * 32 + ((quad ^ sw) * 8)];
#pragma unroll
        for (int j = 0; j < 4; ++j)
            bfr[j] = *(const bf16x8*)&Btile[(wn * 64 + j * 16 + l16) * 32 + ((quad ^ sw) * 8)];
#pragma unroll
        for (int i = 0; i < 4; ++i)
#pragma unroll
            for (int j = 0; j < 4; ++j)
                acc[i][j] = __builtin_amdgcn_mfma_f32_16x16x32_bf16(af[i], bfr[j], acc[i][j], 0, 0, 0);
        __syncthreads();
    }
}

// ---------------------------------------------------------------------------
__global__ __launch_bounds__(256)
void convert_x_kernel(const float* __restrict__ x, bf16_t* __restrict__ xb)
{
    const size_t i = ((size_t)blockIdx.x * 256 + threadIdx.x) * 8;
    float4 a = *(const float4*)&x[i];
    float4 b = *(const float4*)&x[i + 4];
    bf16x8 o;
    o[0] = (bf16_t)a.x; o[1] = (bf16_t)a.y; o[2] = (bf16_t)a.z; o[3] = (bf16_t)a.w;
    o[4] = (bf16_t)b.x; o[5] = (bf16_t)b.y; o[6] = (bf16_t)b.z; o[7] = (bf16_t)b.w;
    *(bf16x8*)&xb[i] = o;
}

// W [1024x1024] fp32 -> WT [1024x1024] bf16 transposed
__global__ __launch_bounds__(256)
void transpose_w_kernel(const float* __restrict__ W, bf16_t* __restrict__ WT)
{
    __shared__ float t[32][33];
    const int k0 = blockIdx.y * 32, n0 = blockIdx.x * 32;
    const int r = threadIdx.x >> 3, c4 = (threadIdx.x & 7) * 4;
    float4 v = *(const float4*)&W[(size_t)(k0 + r) * 1024 + n0 + c4];
    t[r][c4 + 0] = v.x; t[r][c4 + 1] = v.y; t[r][c4 + 2] = v.z; t[r][c4 + 3] = v.w;
    __syncthreads();
    bf16x4 o;
#pragma unroll
    for (int j = 0; j < 4; ++j) o[j] = (bf16_t)t[c4 + j][r];
    *(bf16x4*)&WT[(size_t)(n0 + r) * 1024 + k0 + c4] = o;
}

// V (ldv-strided rows) -> VT [B][D][L]
__global__ __launch_bounds__(256)
void transpose_v_kernel(const bf16_t* __restrict__ V, bf16_t* __restrict__ VT,
                        int L, int Dd, int ldv)
{
    __shared__ bf16_t t[32][34];
    const int b = blockIdx.z;
    const int l0 = blockIdx.x * 32, d0 = blockIdx.y * 32;
    const bf16_t* Vb = V + (size_t)b * L * ldv;
    bf16_t* VTb = VT + (size_t)b * Dd * L;
    const int r = threadIdx.x >> 3, c4 = (threadIdx.x & 7) * 4;
    bf16x4 v = *(const bf16x4*)&Vb[(size_t)(l0 + r) * ldv + d0 + c4];
#pragma unroll
    for (int j = 0; j < 4; ++j) t[r][c4 + j] = v[j];
    __syncthreads();
    bf16x4 o;
#pragma unroll
    for (int j = 0; j < 4; ++j) o[j] = t[c4 + j][r];
    *(bf16x4*)&VTb[(size_t)(d0 + r) * L + l0 + c4] = o;
}

// ---------------------------------------------------------------------------
// Fused QKV projection: C[M,3072] bf16 = A[M,1024] x WT[3072,1024]^T + bias
// ---------------------------------------------------------------------------
__global__ __launch_bounds__(256)
void gemm_qkv_kernel(const bf16_t* __restrict__ A, const bf16_t* __restrict__ Bt,
                     const float* __restrict__ bq, const float* __restrict__ bk,
                     const float* __restrict__ bv, bf16_t* __restrict__ C,
                     int N, int Kd)
{
    __shared__ bf16_t Atile[128 * 32];
    __shared__ bf16_t Btile[128 * 32];
    const int tid = threadIdx.x;
    const int m0 = blockIdx.y * 128, n0 = blockIdx.x * 128;

    f32x4 acc[4][4];
#pragma unroll
    for (int i = 0; i < 4; ++i)
#pragma unroll
        for (int j = 0; j < 4; ++j) acc[i][j] = (f32x4)(0.0f);

    nt_mainloop(A + (size_t)m0 * Kd, Bt + (size_t)n0 * Kd, Kd, Kd, Kd / 32,
                Atile, Btile, tid, acc);

    const int w = tid >> 6, lane = tid & 63;
    const int wm = w & 1, wn = w >> 1, quad = lane >> 4, l16 = lane & 15;
#pragma unroll
    for (int j = 0; j < 4; ++j) {
        const int col = n0 + wn * 64 + j * 16 + l16;
        const float* bp = (col < 1024) ? bq : (col < 2048) ? bk : bv;
        const float bval = bp[col & 1023];
#pragma unroll
        for (int i = 0; i < 4; ++i) {
#pragma unroll
            for (int r = 0; r < 4; ++r) {
                const int row = m0 + wm * 64 + i * 16 + quad * 4 + r;
                C[(size_t)row * N + col] = (bf16_t)(acc[i][j][r] + bval);
            }
        }
    }
}

// ---------------------------------------------------------------------------
// Scores, triangular-only launch: blockIdx.x in [0,136) -> (it,jt), jt<=it.
// S fp32 written only for lower-triangular tiles; masks in reference order.
// ---------------------------------------------------------------------------
__global__ __launch_bounds__(256)
void scores_mfma_kernel(const bf16_t* __restrict__ Q, const bf16_t* __restrict__ K,
                        int ldq, const int* __restrict__ lengths,
                        float* __restrict__ S, int L, int Dd, float alpha)
{
    const int b = blockIdx.z;
    const int len = lengths[b];
    int it = (int)((sqrtf(8.0f * blockIdx.x + 1.0f) - 1.0f) * 0.5f);
    while ((it + 1) * (it + 2) / 2 <= (int)blockIdx.x) ++it;
    while (it * (it + 1) / 2 > (int)blockIdx.x) --it;
    const int jt = blockIdx.x - it * (it + 1) / 2;
    const int m0 = it * 128, n0 = jt * 128;
    float* Sb = S + (size_t)b * L * L;
    const int tid = threadIdx.x;

    __shared__ bf16_t Atile[128 * 32];
    __shared__ bf16_t Btile[128 * 32];
    f32x4 acc[4][4];
#pragma unroll
    for (int i = 0; i < 4; ++i)
#pragma unroll
        for (int j = 0; j < 4; ++j) acc[i][j] = (f32x4)(0.0f);

    const bf16_t* Qb = Q + (size_t)b * L * ldq + (size_t)m0 * ldq;
    const bf16_t* Kb = K + (size_t)b * L * ldq + (size_t)n0 * ldq;
    nt_mainloop(Qb, Kb, ldq, ldq, Dd / 32, Atile, Btile, tid, acc);

    const int w = tid >> 6, lane = tid & 63;
    const int wm = w & 1, wn = w >> 1, quad = lane >> 4, l16 = lane & 15;
#pragma unroll
    for (int i = 0; i < 4; ++i) {
#pragma unroll
        for (int j = 0; j < 4; ++j) {
            const int col = n0 + wn * 64 + j * 16 + l16;
#pragma unroll
            for (int r = 0; r < 4; ++r) {
                const int row = m0 + wm * 64 + i * 16 + quad * 4 + r;
                float s = acc[i][j][r] * alpha;
                if (col > row) s += NEGV;                 // causal first
                if (row >= len || col >= len) s += NEGV;  // then length mask
                Sb[(size_t)row * L + col] = s;
            }
        }
    }
}

// ---------------------------------------------------------------------------
// Row softmax, causally bounded: reads S[0,bound), writes P[0,bound) bf16
// where bound = round_up(i+1, 128). PV never reads beyond bound.
// ---------------------------------------------------------------------------
__global__ __launch_bounds__(256)
void softmax_kernel(const float* __restrict__ S, bf16_t* __restrict__ P,
                    int L, int ldp)
{
    __shared__ float red[8];
    const int i = blockIdx.x;
    const int bound = ((i >> 7) + 1) << 7;
    const float* row = S + ((size_t)blockIdx.y * L + i) * L;
    bf16_t* prow = P + ((size_t)blockIdx.y * L + i) * ldp;
    const int t = threadIdx.x;
    const int w = t >> 6, lane = t & 63;
    const int j8 = t * 8;
    const bool act = j8 < bound;

    float v[8];
    float m = -3.0e38f;
    if (act) {
        float4 a = *(const float4*)&row[j8];
        float4 b = *(const float4*)&row[j8 + 4];
        v[0] = a.x; v[1] = a.y; v[2] = a.z; v[3] = a.w;
        v[4] = b.x; v[5] = b.y; v[6] = b.z; v[7] = b.w;
#pragma unroll
        for (int j = 0; j < 8; ++j) m = fmaxf(m, v[j]);
    }
#pragma unroll
    for (int off = 32; off > 0; off >>= 1) m = fmaxf(m, __shfl_down(m, off, 64));
    if (lane == 0) red[w] = m;
    __syncthreads();
    m = fmaxf(fmaxf(red[0], red[1]), fmaxf(red[2], red[3]));

    float s = 0.f;
    if (act) {
#pragma unroll
        for (int j = 0; j < 8; ++j) {
            v[j] = __expf(v[j] - m);
            s += v[j];
        }
    }
#pragma unroll
    for (int off = 32; off > 0; off >>= 1) s += __shfl_down(s, off, 64);
    if (lane == 0) red[4 + w] = s;
    __syncthreads();
    s = red[4] + red[5] + red[6] + red[7];

    if (act) {
        const float inv = 1.0f / s;
        bf16x8 o;
#pragma unroll
        for (int j = 0; j < 8; ++j) o[j] = (bf16_t)(v[j] * inv);
        *(bf16x8*)&prow[j8] = o;
    }
}

// ---------------------------------------------------------------------------
// PV: O[b][L,D] fp32 = P[b][L,L] x VT[b][D,L]^T, causal k-limit, heavy-first
// ---------------------------------------------------------------------------
__global__ __launch_bounds__(256)
void pv_mfma_kernel(const bf16_t* __restrict__ P, int ldp,
                    const bf16_t* __restrict__ VT,
                    float* __restrict__ O, int L, int Dd)
{
    __shared__ bf16_t Atile[128 * 32];
    __shared__ bf16_t Btile[128 * 32];
    const int b = blockIdx.z;
    const int mt = gridDim.y - 1 - blockIdx.y;   // heavy tiles dispatch first
    const int m0 = mt * 128, n0 = blockIdx.x * 128;
    const int tid = threadIdx.x;

    f32x4 acc[4][4];
#pragma unroll
    for (int i = 0; i < 4; ++i)
#pragma unroll
        for (int j = 0; j < 4; ++j) acc[i][j] = (f32x4)(0.0f);

    const int ksteps = (m0 + 128) / 32;   // P[i][j]==0 for j>i
    const bf16_t* Pb = P + (size_t)b * L * ldp + (size_t)m0 * ldp;
    const bf16_t* Vb = VT + (size_t)b * Dd * L + (size_t)n0 * L;
    nt_mainloop(Pb, Vb, ldp, L, ksteps, Atile, Btile, tid, acc);

    float* Ob = O + (size_t)b * L * Dd;
    const int w = tid >> 6, lane = tid & 63;
    const int wm = w & 1, wn = w >> 1, quad = lane >> 4, l16 = lane & 15;
#pragma unroll
    for (int i = 0; i < 4; ++i) {
#pragma unroll
        for (int j = 0; j < 4; ++j) {
            const int col = n0 + wn * 64 + j * 16 + l16;
#pragma unroll
            for (int r = 0; r < 4; ++r) {
                const int row = m0 + wm * 64 + i * 16 + quad * 4 + r;
                Ob[(size_t)row * Dd + col] = acc[i][j][r];
            }
        }
    }
}

// ---------------------------------------------------------------------------
extern "C" void kernel_launch(void* const* d_in, const int* in_sizes, int n_in,
                              void* d_out, int out_size, void* d_ws, size_t ws_size,
                              hipStream_t stream)
{
    const float* x  = (const float*)d_in[0];
    const float* Wq = (const float*)d_in[1];
    const float* bq = (const float*)d_in[2];
    const float* Wk = (const float*)d_in[3];
    const float* bk = (const float*)d_in[4];
    const float* Wv = (const float*)d_in[5];
    const float* bv = (const float*)d_in[6];
    const int*  len = (const int*)d_in[7];
    float* out = (float*)d_out;

    const int B = 4, L = 2048, D = 1024;
    const int M = B * L;     // 8192
    const int N3 = 3 * D;    // 3072

    // Workspace (134 MB):
    //  xb  [M][1024] bf16 = 16 MB   (reused as VT [B][D][L] after projections)
    //  WT  [3072][1024] bf16 = 6 MB (Wq^T | Wk^T | Wv^T)
    //  QKV [M][3072] bf16 = 48 MB   (cols 0:Q 1024:K 2048:V; rows reused as P)
    //  S   [B][L][L] fp32 = 64 MB   (lower-triangular tiles only)
    bf16_t* xb  = (bf16_t*)d_ws;
    bf16_t* WT  = xb + (size_t)M * D;
    bf16_t* QKV = WT + (size_t)N3 * D;
    float*  S   = (float*)(QKV + (size_t)M * N3);
    bf16_t* VT  = xb;        // alias (xb dead after projections)
    bf16_t* P   = QKV;       // alias (Q,K cols dead after scores), ld = 3072

    // 1) x -> bf16
    convert_x_kernel<<<(M * D) / 2048, 256, 0, stream>>>(x, xb);

    // 2) W transposes into WT sections
    dim3 gt(32, 32);
    transpose_w_kernel<<<gt, 256, 0, stream>>>(Wq, WT);
    transpose_w_kernel<<<gt, 256, 0, stream>>>(Wk, WT + (size_t)D * D);
    transpose_w_kernel<<<gt, 256, 0, stream>>>(Wv, WT + (size_t)2 * D * D);

    // 3) fused QKV projection
    gemm_qkv_kernel<<<dim3(N3 / 128, M / 128), 256, 0, stream>>>(
        xb, WT, bq, bk, bv, QKV, N3, D);

    // 4) V transpose (V = QKV cols [2048,3072)) into dead xb
    transpose_v_kernel<<<dim3(L / 32, D / 32, B), 256, 0, stream>>>(
        QKV + 2048, VT, L, D, N3);

    // 5) scores, triangular tiles only
    scores_mfma_kernel<<<dim3(136, 1, B), 256, 0, stream>>>(
        QKV, QKV + 1024, N3, len, S, L, D, 0.03125f);

    // 6) bounded softmax -> P (aliased into QKV rows, cols [0,2048))
    softmax_kernel<<<dim3(L, B), 256, 0, stream>>>(S, P, L, N3);

    // 7) O = P @ V, causal k-limit, heavy tiles first
    pv_mfma_kernel<<<dim3(D / 128, L / 128, B), 256, 0, stream>>>(
        P, N3, VT, out, L, D);
}

// Round 6
// 270.497 us; speedup vs baseline: 5.3740x; 1.1225x over previous
//
#include <hip/hip_runtime.h>

#define NEGV (-1.0e9f)

typedef __bf16 bf16_t;
typedef __bf16 bf16x8 __attribute__((ext_vector_type(8)));
typedef __bf16 bf16x4 __attribute__((ext_vector_type(4)));
typedef float  f32x4  __attribute__((ext_vector_type(4)));

// async global->LDS, 16B per lane; LDS dest is wave-uniform base + lane*16
__device__ __forceinline__ void gld16(const void* g, void* l) {
    __builtin_amdgcn_global_load_lds(
        (const __attribute__((address_space(1))) void*)g,
        (__attribute__((address_space(3))) void*)l, 16, 0, 0);
}

// ---------------------------------------------------------------------------
// NT MFMA mainloop, double-buffered LDS, ONE barrier per K-step.
//   C[128,128] tile = A[128,K] x B[128,K]^T (row-major, k-contiguous rows).
// 256 threads = 4 waves (2x2); each wave 64x64 via 4x4 mfma_f32_16x16x32_bf16.
//
// Pipeline: loads for tile k+1 are issued right AFTER the barrier that opens
// step k, so the compiler's mandatory vmcnt(0) drain (before the NEXT barrier)
// lands after a full MFMA phase of in-flight time. Buffer hazard check:
// barrier(k) guarantees all reads of buf[(k)&1^1] (done at k-1) completed
// before any wave overwrites it at step k.
//
// LDS XOR swizzle (kills 8-way ds_read_b128 conflicts): k-chunk c of row r at
// slot c ^ ((r>>1)&3); applied on the global side during staging.
// ---------------------------------------------------------------------------
__device__ __forceinline__ void nt_mainloop_db(
    const bf16_t* __restrict__ A, const bf16_t* __restrict__ B,
    int ldA, int ldB, int numKsteps,
    bf16_t* Atile, bf16_t* Btile,   // each 2 * 128*32
    int tid, f32x4 acc[4][4])
{
    const int w    = tid >> 6;
    const int lane = tid & 63;
    const int wm   = w & 1;
    const int wn   = w >> 1;
    const int srow = lane >> 2;
    const int skc  = ((lane & 3) ^ ((lane >> 3) & 3)) * 8;   // swizzled k-chunk
    const int quad = lane >> 4;
    const int l16  = lane & 15;
    const int sw   = (l16 >> 1) & 3;

    const bf16_t* ga0 = A + (size_t)((w * 2 + 0) * 16 + srow) * ldA + skc;
    const bf16_t* ga1 = A + (size_t)((w * 2 + 1) * 16 + srow) * ldA + skc;
    const bf16_t* gb0 = B + (size_t)((w * 2 + 0) * 16 + srow) * ldB + skc;
    const bf16_t* gb1 = B + (size_t)((w * 2 + 1) * 16 + srow) * ldB + skc;
    const int la0 = (w * 2 + 0) * 16 * 32;
    const int la1 = (w * 2 + 1) * 16 * 32;

    // prologue: stage tile 0 into buffer 0
    gld16(ga0, Atile + la0);
    gld16(ga1, Atile + la1);
    gld16(gb0, Btile + la0);
    gld16(gb1, Btile + la1);
    ga0 += 32; ga1 += 32; gb0 += 32; gb1 += 32;

    for (int kt = 0; kt < numKsteps; ++kt) {
        const int cur = (kt & 1) * (128 * 32);
        const int nxt = ((kt + 1) & 1) * (128 * 32);
        __syncthreads();   // drains own loads (compiler vmcnt) + cross-wave vis
        if (kt + 1 < numKsteps) {
            gld16(ga0, Atile + nxt + la0);
            gld16(ga1, Atile + nxt + la1);
            gld16(gb0, Btile + nxt + la0);
            gld16(gb1, Btile + nxt + la1);
            ga0 += 32; ga1 += 32; gb0 += 32; gb1 += 32;
        }
        bf16x8 af[4], bfr[4];
#pragma unroll
        for (int i = 0; i < 4; ++i)
            af[i] = *(const bf16x8*)&Atile[cur + (wm * 64 + i * 16 + l16) * 32 + ((quad ^ sw) * 8)];
#pragma unroll
        for (int j = 0; j < 4; ++j)
            bfr[j] = *(const bf16x8*)&Btile[cur + (wn * 64 + j * 16 + l16) * 32 + ((quad ^ sw) * 8)];
#pragma unroll
        for (int i = 0; i < 4; ++i)
#pragma unroll
            for (int j = 0; j < 4; ++j)
                acc[i][j] = __builtin_amdgcn_mfma_f32_16x16x32_bf16(af[i], bfr[j], acc[i][j], 0, 0, 0);
    }
}

// ---------------------------------------------------------------------------
__global__ __launch_bounds__(256)
void convert_x_kernel(const float* __restrict__ x, bf16_t* __restrict__ xb)
{
    const size_t i = ((size_t)blockIdx.x * 256 + threadIdx.x) * 8;
    float4 a = *(const float4*)&x[i];
    float4 b = *(const float4*)&x[i + 4];
    bf16x8 o;
    o[0] = (bf16_t)a.x; o[1] = (bf16_t)a.y; o[2] = (bf16_t)a.z; o[3] = (bf16_t)a.w;
    o[4] = (bf16_t)b.x; o[5] = (bf16_t)b.y; o[6] = (bf16_t)b.z; o[7] = (bf16_t)b.w;
    *(bf16x8*)&xb[i] = o;
}

// All three W [1024x1024] fp32 -> WT bf16 transposed, z selects matrix
__global__ __launch_bounds__(256)
void transpose_w_kernel(const float* __restrict__ W0, const float* __restrict__ W1,
                        const float* __restrict__ W2, bf16_t* __restrict__ WT)
{
    __shared__ float t[32][33];
    const float* W = (blockIdx.z == 0) ? W0 : (blockIdx.z == 1) ? W1 : W2;
    bf16_t* WTz = WT + (size_t)blockIdx.z * 1024 * 1024;
    const int k0 = blockIdx.y * 32, n0 = blockIdx.x * 32;
    const int r = threadIdx.x >> 3, c4 = (threadIdx.x & 7) * 4;
    float4 v = *(const float4*)&W[(size_t)(k0 + r) * 1024 + n0 + c4];
    t[r][c4 + 0] = v.x; t[r][c4 + 1] = v.y; t[r][c4 + 2] = v.z; t[r][c4 + 3] = v.w;
    __syncthreads();
    bf16x4 o;
#pragma unroll
    for (int j = 0; j < 4; ++j) o[j] = (bf16_t)t[c4 + j][r];
    *(bf16x4*)&WTz[(size_t)(n0 + r) * 1024 + k0 + c4] = o;
}

// ---------------------------------------------------------------------------
// QK projection: C[M,2048] bf16 = xb[M,1024] x WT[2048,1024]^T + (bq|bk)
// ---------------------------------------------------------------------------
__global__ __launch_bounds__(256)
void gemm_qk_kernel(const bf16_t* __restrict__ A, const bf16_t* __restrict__ Bt,
                    const float* __restrict__ bq, const float* __restrict__ bk,
                    bf16_t* __restrict__ C, int N, int Kd)
{
    __shared__ bf16_t Atile[2 * 128 * 32];
    __shared__ bf16_t Btile[2 * 128 * 32];
    const int tid = threadIdx.x;
    const int m0 = blockIdx.y * 128, n0 = blockIdx.x * 128;

    f32x4 acc[4][4];
#pragma unroll
    for (int i = 0; i < 4; ++i)
#pragma unroll
        for (int j = 0; j < 4; ++j) acc[i][j] = (f32x4)(0.0f);

    nt_mainloop_db(A + (size_t)m0 * Kd, Bt + (size_t)n0 * Kd, Kd, Kd, Kd / 32,
                   Atile, Btile, tid, acc);

    const int w = tid >> 6, lane = tid & 63;
    const int wm = w & 1, wn = w >> 1, quad = lane >> 4, l16 = lane & 15;
#pragma unroll
    for (int j = 0; j < 4; ++j) {
        const int col = n0 + wn * 64 + j * 16 + l16;
        const float bval = (col < 1024) ? bq[col] : bk[col - 1024];
#pragma unroll
        for (int i = 0; i < 4; ++i) {
#pragma unroll
            for (int r = 0; r < 4; ++r) {
                const int row = m0 + wm * 64 + i * 16 + quad * 4 + r;
                C[(size_t)row * N + col] = (bf16_t)(acc[i][j][r] + bval);
            }
        }
    }
}

// ---------------------------------------------------------------------------
// V^T projection: VT[1024, 8192] bf16 = WvT[1024,1024] x xb[8192,1024]^T + bv
// (row d, col = b*2048+l  ->  layout [d][b][l], per-batch ld = 8192)
// ---------------------------------------------------------------------------
__global__ __launch_bounds__(256)
void gemm_vt_kernel(const bf16_t* __restrict__ WvT, const bf16_t* __restrict__ xb,
                    const float* __restrict__ bv, bf16_t* __restrict__ VT,
                    int N, int Kd)
{
    __shared__ bf16_t Atile[2 * 128 * 32];
    __shared__ bf16_t Btile[2 * 128 * 32];
    const int tid = threadIdx.x;
    const int m0 = blockIdx.y * 128, n0 = blockIdx.x * 128;

    f32x4 acc[4][4];
#pragma unroll
    for (int i = 0; i < 4; ++i)
#pragma unroll
        for (int j = 0; j < 4; ++j) acc[i][j] = (f32x4)(0.0f);

    nt_mainloop_db(WvT + (size_t)m0 * Kd, xb + (size_t)n0 * Kd, Kd, Kd, Kd / 32,
                   Atile, Btile, tid, acc);

    const int w = tid >> 6, lane = tid & 63;
    const int wm = w & 1, wn = w >> 1, quad = lane >> 4, l16 = lane & 15;
#pragma unroll
    for (int i = 0; i < 4; ++i) {
#pragma unroll
        for (int r = 0; r < 4; ++r) {
            const int row = m0 + wm * 64 + i * 16 + quad * 4 + r;   // d index
            const float bval = bv[row];
#pragma unroll
            for (int j = 0; j < 4; ++j) {
                const int col = n0 + wn * 64 + j * 16 + l16;        // b*L + l
                VT[(size_t)row * N + col] = (bf16_t)(acc[i][j][r] + bval);
            }
        }
    }
}

// ---------------------------------------------------------------------------
// Scores, triangular-only launch: blockIdx.x in [0,136) -> (it,jt), jt<=it.
// Masks applied in reference order (fp32 -1e9 adds) in the epilogue.
// ---------------------------------------------------------------------------
__global__ __launch_bounds__(256)
void scores_mfma_kernel(const bf16_t* __restrict__ Q, const bf16_t* __restrict__ K,
                        int ldq, const int* __restrict__ lengths,
                        float* __restrict__ S, int L, int Dd, float alpha)
{
    const int b = blockIdx.z;
    const int len = lengths[b];
    int it = (int)((sqrtf(8.0f * blockIdx.x + 1.0f) - 1.0f) * 0.5f);
    while ((it + 1) * (it + 2) / 2 <= (int)blockIdx.x) ++it;
    while (it * (it + 1) / 2 > (int)blockIdx.x) --it;
    const int jt = blockIdx.x - it * (it + 1) / 2;
    const int m0 = it * 128, n0 = jt * 128;
    float* Sb = S + (size_t)b * L * L;
    const int tid = threadIdx.x;

    __shared__ bf16_t Atile[2 * 128 * 32];
    __shared__ bf16_t Btile[2 * 128 * 32];
    f32x4 acc[4][4];
#pragma unroll
    for (int i = 0; i < 4; ++i)
#pragma unroll
        for (int j = 0; j < 4; ++j) acc[i][j] = (f32x4)(0.0f);

    const bf16_t* Qb = Q + (size_t)b * L * ldq + (size_t)m0 * ldq;
    const bf16_t* Kb = K + (size_t)b * L * ldq + (size_t)n0 * ldq;
    nt_mainloop_db(Qb, Kb, ldq, ldq, Dd / 32, Atile, Btile, tid, acc);

    const int w = tid >> 6, lane = tid & 63;
    const int wm = w & 1, wn = w >> 1, quad = lane >> 4, l16 = lane & 15;
#pragma unroll
    for (int i = 0; i < 4; ++i) {
#pragma unroll
        for (int j = 0; j < 4; ++j) {
            const int col = n0 + wn * 64 + j * 16 + l16;
#pragma unroll
            for (int r = 0; r < 4; ++r) {
                const int row = m0 + wm * 64 + i * 16 + quad * 4 + r;
                float s = acc[i][j][r] * alpha;
                if (col > row) s += NEGV;                 // causal first
                if (row >= len || col >= len) s += NEGV;  // then length mask
                Sb[(size_t)row * L + col] = s;
            }
        }
    }
}

// ---------------------------------------------------------------------------
// Row softmax, causally bounded: reads S[0,bound), writes P[0,bound) bf16,
// bound = round_up(i+1,128). PV's k-limit never reads past bound.
// ---------------------------------------------------------------------------
__global__ __launch_bounds__(256)
void softmax_kernel(const float* __restrict__ S, bf16_t* __restrict__ P,
                    int L, int ldp)
{
    __shared__ float red[8];
    const int i = blockIdx.x;
    const int bound = ((i >> 7) + 1) << 7;
    const float* row = S + ((size_t)blockIdx.y * L + i) * L;
    bf16_t* prow = P + ((size_t)blockIdx.y * L + i) * ldp;
    const int t = threadIdx.x;
    const int w = t >> 6, lane = t & 63;
    const int j8 = t * 8;
    const bool act = j8 < bound;

    float v[8];
    float m = -3.0e38f;
    if (act) {
        float4 a = *(const float4*)&row[j8];
        float4 b = *(const float4*)&row[j8 + 4];
        v[0] = a.x; v[1] = a.y; v[2] = a.z; v[3] = a.w;
        v[4] = b.x; v[5] = b.y; v[6] = b.z; v[7] = b.w;
#pragma unroll
        for (int j = 0; j < 8; ++j) m = fmaxf(m, v[j]);
    }
#pragma unroll
    for (int off = 32; off > 0; off >>= 1) m = fmaxf(m, __shfl_down(m, off, 64));
    if (lane == 0) red[w] = m;
    __syncthreads();
    m = fmaxf(fmaxf(red[0], red[1]), fmaxf(red[2], red[3]));

    float s = 0.f;
    if (act) {
#pragma unroll
        for (int j = 0; j < 8; ++j) {
            v[j] = __expf(v[j] - m);
            s += v[j];
        }
    }
#pragma unroll
    for (int off = 32; off > 0; off >>= 1) s += __shfl_down(s, off, 64);
    if (lane == 0) red[4 + w] = s;
    __syncthreads();
    s = red[4] + red[5] + red[6] + red[7];

    if (act) {
        const float inv = 1.0f / s;
        bf16x8 o;
#pragma unroll
        for (int j = 0; j < 8; ++j) o[j] = (bf16_t)(v[j] * inv);
        *(bf16x8*)&prow[j8] = o;
    }
}

// ---------------------------------------------------------------------------
// PV: O[b][L,D] fp32 = P[b][L,L] x V^T (VT layout [d][b][l], ld 8192),
// causal k-limit, heavy tiles dispatched first.
// ---------------------------------------------------------------------------
__global__ __launch_bounds__(256)
void pv_mfma_kernel(const bf16_t* __restrict__ P, int ldp,
                    const bf16_t* __restrict__ VT, int ldv,
                    float* __restrict__ O, int L, int Dd)
{
    __shared__ bf16_t Atile[2 * 128 * 32];
    __shared__ bf16_t Btile[2 * 128 * 32];
    const int b = blockIdx.z;
    const int mt = gridDim.y - 1 - blockIdx.y;   // heavy first
    const int m0 = mt * 128, n0 = blockIdx.x * 128;
    const int tid = threadIdx.x;

    f32x4 acc[4][4];
#pragma unroll
    for (int i = 0; i < 4; ++i)
#pragma unroll
        for (int j = 0; j < 4; ++j) acc[i][j] = (f32x4)(0.0f);

    const int ksteps = (m0 + 128) / 32;   // P[i][j]==0 for j>i
    const bf16_t* Pb = P + (size_t)b * L * ldp + (size_t)m0 * ldp;
    const bf16_t* Vb = VT + (size_t)b * L + (size_t)n0 * ldv;
    nt_mainloop_db(Pb, Vb, ldp, ldv, ksteps, Atile, Btile, tid, acc);

    float* Ob = O + (size_t)b * L * Dd;
    const int w = tid >> 6, lane = tid & 63;
    const int wm = w & 1, wn = w >> 1, quad = lane >> 4, l16 = lane & 15;
#pragma unroll
    for (int i = 0; i < 4; ++i) {
#pragma unroll
        for (int j = 0; j < 4; ++j) {
            const int col = n0 + wn * 64 + j * 16 + l16;
#pragma unroll
            for (int r = 0; r < 4; ++r) {
                const int row = m0 + wm * 64 + i * 16 + quad * 4 + r;
                Ob[(size_t)row * Dd + col] = acc[i][j][r];
            }
        }
    }
}

// ---------------------------------------------------------------------------
extern "C" void kernel_launch(void* const* d_in, const int* in_sizes, int n_in,
                              void* d_out, int out_size, void* d_ws, size_t ws_size,
                              hipStream_t stream)
{
    const float* x  = (const float*)d_in[0];
    const float* Wq = (const float*)d_in[1];
    const float* bq = (const float*)d_in[2];
    const float* Wk = (const float*)d_in[3];
    const float* bk = (const float*)d_in[4];
    const float* Wv = (const float*)d_in[5];
    const float* bv = (const float*)d_in[6];
    const int*  len = (const int*)d_in[7];
    float* out = (float*)d_out;

    const int B = 4, L = 2048, D = 1024;
    const int M = B * L;     // 8192
    const int N2 = 2 * D;    // 2048

    // Workspace (140.5 MB):
    //  xb [8192][1024] bf16 = 16 MB
    //  WT [3072][1024] bf16 = 6 MB   (Wq^T | Wk^T | Wv^T)
    //  QK [8192][2048] bf16 = 32 MB  (cols 0:Q 1024:K; rows reused as P, ld 2048)
    //  VT [1024][8192] bf16 = 16 MB  (layout [d][b][l])
    //  S  [4][2048][2048] fp32 = 64 MB (lower-triangular tiles only)
    bf16_t* xb = (bf16_t*)d_ws;
    bf16_t* WT = xb + (size_t)M * D;
    bf16_t* QK = WT + (size_t)3 * D * D;
    bf16_t* VT = QK + (size_t)M * N2;
    float*  S  = (float*)(VT + (size_t)D * M);
    bf16_t* P  = QK;   // alias: Q,K dead after scores; ld = 2048

    // 1) x -> bf16
    convert_x_kernel<<<(M * D) / 2048, 256, 0, stream>>>(x, xb);

    // 2) all W transposes in one launch
    transpose_w_kernel<<<dim3(32, 32, 3), 256, 0, stream>>>(Wq, Wk, Wv, WT);

    // 3) QK projection (N=2048)
    gemm_qk_kernel<<<dim3(N2 / 128, M / 128), 256, 0, stream>>>(
        xb, WT, bq, bk, QK, N2, D);

    // 4) V^T projection (direct, no transpose kernel)
    gemm_vt_kernel<<<dim3(M / 128, D / 128), 256, 0, stream>>>(
        WT + (size_t)2 * D * D, xb, bv, VT, M, D);

    // 5) scores, triangular tiles only
    scores_mfma_kernel<<<dim3(136, 1, B), 256, 0, stream>>>(
        QK, QK + 1024, N2, len, S, L, D, 0.03125f);

    // 6) bounded softmax -> P (aliased over QK rows)
    softmax_kernel<<<dim3(L, B), 256, 0, stream>>>(S, P, L, N2);

    // 7) O = P @ V, causal k-limit, heavy tiles first
    pv_mfma_kernel<<<dim3(D / 128, L / 128, B), 256, 0, stream>>>(
        P, N2, VT, M, out, L, D);
}